// Round 1
// baseline (63.904 us; speedup 1.0000x reference)
//
#include <hip/hip_runtime.h>

#define UNITS   4096
#define IN_DIM  4096
#define LEVELS  16
#define NGROUPS 32
#define BATCH   16

#define UPW   4                 // units per wave
#define WAVES 4                 // waves per block
#define UPB   (UPW * WAVES)     // 16 units per block
#define KSPLIT 4
#define KSLICE (IN_DIM / KSPLIT)   // 1024
#define KPERITER 256               // 64 lanes * 4 elems
#define NITER (KSLICE / KPERITER)  // 4

__global__ __launch_bounds__(256, 2)
void turbo_dense_kernel(const float* __restrict__ inputs,
                        const float* __restrict__ codebooks,
                        const float* __restrict__ scales,
                        const float* __restrict__ residual,
                        const float* __restrict__ bias,
                        const int*   __restrict__ indices,
                        float* __restrict__ out)
{
    __shared__ float cb[UPB * LEVELS];   // 16 units * 16 levels = 1 KiB

    const int tid  = threadIdx.x;
    const int bx   = blockIdx.x;
    const int ub   = bx & 255;           // unit-block id 0..255
    const int ks   = bx >> 8;            // k-slice id 0..3
    const int o_block = ub * UPB;

    // stage this block's 16 codebook rows (256 floats) into LDS
    cb[tid] = codebooks[o_block * LEVELS + tid];
    __syncthreads();

    const int wave = tid >> 6;
    const int lane = tid & 63;
    const int o0   = o_block + wave * UPW;   // wave's first unit
    const int kbase = ks * KSLICE;

    float acc[64];
    #pragma unroll
    for (int i = 0; i < 64; ++i) acc[i] = 0.f;

    const float* cbw = &cb[wave * UPW * LEVELS];

    for (int it = 0; it < NITER; ++it) {
        const int k = kbase + it * KPERITER + lane * 4;
        const int g = k >> 7;                 // group id (uniform per lane quad)

        float w[UPW][4];
        #pragma unroll
        for (int u = 0; u < UPW; ++u) {
            const int o = o0 + u;
            const int4   idx4 = *reinterpret_cast<const int4*>(&indices[(size_t)o * IN_DIM + k]);
            const float4 r4   = *reinterpret_cast<const float4*>(&residual[(size_t)o * IN_DIM + k]);
            const float  s    = scales[o * NGROUPS + g];
            w[u][0] = fmaf(cbw[u * LEVELS + idx4.x], s, r4.x);
            w[u][1] = fmaf(cbw[u * LEVELS + idx4.y], s, r4.y);
            w[u][2] = fmaf(cbw[u * LEVELS + idx4.z], s, r4.z);
            w[u][3] = fmaf(cbw[u * LEVELS + idx4.w], s, r4.w);
        }

        #pragma unroll
        for (int b = 0; b < BATCH; ++b) {
            const float4 in4 = *reinterpret_cast<const float4*>(&inputs[b * IN_DIM + k]);
            #pragma unroll
            for (int u = 0; u < UPW; ++u) {
                acc[b * UPW + u] = fmaf(in4.x, w[u][0], acc[b * UPW + u]);
                acc[b * UPW + u] = fmaf(in4.y, w[u][1], acc[b * UPW + u]);
                acc[b * UPW + u] = fmaf(in4.z, w[u][2], acc[b * UPW + u]);
                acc[b * UPW + u] = fmaf(in4.w, w[u][3], acc[b * UPW + u]);
            }
        }
    }

    // fold-reduce across 64 lanes: lane l ends with total of acc[l]
    // (63 shfl + 63 add total)
#define FOLD(S, N)                                         \
    {                                                      \
        const bool hi = (lane & (S)) != 0;                 \
        _Pragma("unroll")                                  \
        for (int t = 0; t < (N) / 2; ++t) {                \
            float a  = acc[2 * t];                         \
            float b2 = acc[2 * t + 1];                     \
            float send = hi ? a : b2;                      \
            float recv = __shfl_xor(send, (S));            \
            acc[t] = (hi ? b2 : a) + recv;                 \
        }                                                  \
    }
    FOLD(1, 64)
    FOLD(2, 32)
    FOLD(4, 16)
    FOLD(8, 8)
    FOLD(16, 4)
    FOLD(32, 2)
#undef FOLD

    // lane holds the full k-slice partial for acc index i == lane:
    // i = b*UPW + u  ->  b = lane>>2, u = lane&3
    const int b_ = lane >> 2;
    const int u_ = lane & 3;
    float v = acc[0];
    if (ks == 0) v += bias[o0 + u_];
    atomicAdd(&out[b_ * UNITS + o0 + u_], v);
}

extern "C" void kernel_launch(void* const* d_in, const int* in_sizes, int n_in,
                              void* d_out, int out_size, void* d_ws, size_t ws_size,
                              hipStream_t stream)
{
    const float* inputs    = (const float*)d_in[0];
    const float* codebooks = (const float*)d_in[1];
    const float* scales    = (const float*)d_in[2];
    const float* residual  = (const float*)d_in[3];
    const float* bias      = (const float*)d_in[4];
    const int*   indices   = (const int*)d_in[5];
    float* out = (float*)d_out;

    // out is accumulated via atomics -> must start from zero every call
    hipMemsetAsync(d_out, 0, (size_t)out_size * sizeof(float), stream);

    dim3 grid((UNITS / UPB) * KSPLIT);   // 256 unit-blocks * 4 k-slices = 1024
    dim3 block(256);
    turbo_dense_kernel<<<grid, block, 0, stream>>>(inputs, codebooks, scales,
                                                   residual, bias, indices, out);
}

// Round 2
// 48.342 us; speedup vs baseline: 1.3219x; 1.3219x over previous
//
#include <hip/hip_runtime.h>

#define UNITS   4096
#define IN_DIM  4096
#define LEVELS  16
#define NGROUPS 32
#define BATCH   16

#define UPW   4                  // units per wave
#define WAVES 4                  // waves per block
#define UPB   (UPW * WAVES)      // 16 units per block
#define KSPLIT 16
#define KSLICE (IN_DIM / KSPLIT) // 256 = 64 lanes * 4 elems -> single shot

__global__ __launch_bounds__(256, 4)
void turbo_dense_kernel(const float* __restrict__ inputs,
                        const float* __restrict__ codebooks,
                        const float* __restrict__ scales,
                        const float* __restrict__ residual,
                        const float* __restrict__ bias,
                        const int*   __restrict__ indices,
                        float* __restrict__ out)
{
    __shared__ float cb[UPB * LEVELS];   // 16 units * 16 levels = 1 KiB

    const int tid  = threadIdx.x;
    const int bx   = blockIdx.x;
    const int ub   = bx & 255;           // unit-block id 0..255
    const int ks   = bx >> 8;            // k-slice id 0..15
    const int o_block = ub * UPB;

    cb[tid] = codebooks[o_block * LEVELS + tid];
    __syncthreads();

    const int wave = tid >> 6;
    const int lane = tid & 63;
    const int o0   = o_block + wave * UPW;
    const int k    = ks * KSLICE + lane * 4;
    const int g    = k >> 7;             // group id for this lane's quad

    // Issue the lane's ENTIRE weight stream first: 8 x 16B global loads +
    // 4 scale loads, all independent -> deep vmcnt queue before any use.
    int4   idx[UPW];
    float4 r[UPW];
    float  s[UPW];
    #pragma unroll
    for (int u = 0; u < UPW; ++u) {
        const size_t off = (size_t)(o0 + u) * IN_DIM + k;
        idx[u] = *reinterpret_cast<const int4*>(&indices[off]);
        r[u]   = *reinterpret_cast<const float4*>(&residual[off]);
        s[u]   = scales[(o0 + u) * NGROUPS + g];
    }

    // Dequantize: LDS gather (latency hidden by other waves) + fma
    const float* cbw = &cb[wave * UPW * LEVELS];
    float w[UPW][4];
    #pragma unroll
    for (int u = 0; u < UPW; ++u) {
        w[u][0] = fmaf(cbw[u * LEVELS + idx[u].x], s[u], r[u].x);
        w[u][1] = fmaf(cbw[u * LEVELS + idx[u].y], s[u], r[u].y);
        w[u][2] = fmaf(cbw[u * LEVELS + idx[u].z], s[u], r[u].z);
        w[u][3] = fmaf(cbw[u * LEVELS + idx[u].w], s[u], r[u].w);
    }

    // Batch FMAs; input loads are independent of the gather chain, the
    // 128-VGPR budget lets the compiler hoist several ahead.
    float acc[BATCH * UPW];
    #pragma unroll
    for (int b = 0; b < BATCH; ++b) {
        const float4 in4 = *reinterpret_cast<const float4*>(&inputs[b * IN_DIM + k]);
        #pragma unroll
        for (int u = 0; u < UPW; ++u) {
            float a = in4.x * w[u][0];
            a = fmaf(in4.y, w[u][1], a);
            a = fmaf(in4.z, w[u][2], a);
            a = fmaf(in4.w, w[u][3], a);
            acc[b * UPW + u] = a;
        }
    }

    // fold-reduce across 64 lanes: lane l ends with total of acc[l]
#define FOLD(S, N)                                         \
    {                                                      \
        const bool hi = (lane & (S)) != 0;                 \
        _Pragma("unroll")                                  \
        for (int t = 0; t < (N) / 2; ++t) {                \
            float a  = acc[2 * t];                         \
            float b2 = acc[2 * t + 1];                     \
            float send = hi ? a : b2;                      \
            float recv = __shfl_xor(send, (S));            \
            acc[t] = (hi ? b2 : a) + recv;                 \
        }                                                  \
    }
    FOLD(1, 64)
    FOLD(2, 32)
    FOLD(4, 16)
    FOLD(8, 8)
    FOLD(16, 4)
    FOLD(32, 2)
#undef FOLD

    // acc index i == lane: i = b*UPW + u  ->  b = lane>>2, u = lane&3
    const int b_ = lane >> 2;
    const int u_ = lane & 3;
    float v = acc[0];
    if (ks == 0) v += bias[o0 + u_];
    atomicAdd(&out[b_ * UNITS + o0 + u_], v);
}

extern "C" void kernel_launch(void* const* d_in, const int* in_sizes, int n_in,
                              void* d_out, int out_size, void* d_ws, size_t ws_size,
                              hipStream_t stream)
{
    const float* inputs    = (const float*)d_in[0];
    const float* codebooks = (const float*)d_in[1];
    const float* scales    = (const float*)d_in[2];
    const float* residual  = (const float*)d_in[3];
    const float* bias      = (const float*)d_in[4];
    const int*   indices   = (const int*)d_in[5];
    float* out = (float*)d_out;

    // out is accumulated via atomics -> must start from zero every call
    hipMemsetAsync(d_out, 0, (size_t)out_size * sizeof(float), stream);

    dim3 grid((UNITS / UPB) * KSPLIT);   // 256 unit-blocks * 16 k-slices = 4096
    dim3 block(256);
    turbo_dense_kernel<<<grid, block, 0, stream>>>(inputs, codebooks, scales,
                                                   residual, bias, indices, out);
}

// Round 3
// 48.109 us; speedup vs baseline: 1.3283x; 1.0048x over previous
//
#include <hip/hip_runtime.h>

#define UNITS   4096
#define IN_DIM  4096
#define LEVELS  16
#define NGROUPS 32
#define BATCH   16

#define UPW   4                  // units per wave
#define WAVES 4                  // waves per block
#define UPB   (UPW * WAVES)      // 16 units per block
#define KSPLIT 8
#define KSLICE (IN_DIM / KSPLIT) // 512
#define KQ    256                // k per inner iter (64 lanes * 4)
#define NITER (KSLICE / KQ)      // 2

__global__ __launch_bounds__(256, 4)
void turbo_dense_kernel(const float* __restrict__ inputs,
                        const float* __restrict__ codebooks,
                        const float* __restrict__ scales,
                        const float* __restrict__ residual,
                        const float* __restrict__ bias,
                        const int*   __restrict__ indices,
                        float* __restrict__ out)
{
    __shared__ float cb[UPB * LEVELS];   // 16 units * 16 levels = 1 KiB

    const int tid  = threadIdx.x;
    const int bx   = blockIdx.x;
    const int ub   = bx & 255;           // unit-block id 0..255
    const int ks   = bx >> 8;            // k-slice id 0..7
    const int o_block = ub * UPB;

    const int wave = tid >> 6;
    const int lane = tid & 63;
    const int o0   = o_block + wave * UPW;
    const int kbase = ks * KSLICE + lane * 4;

    // stage codebooks (does not block the weight loads below)
    cb[tid] = codebooks[o_block * LEVELS + tid];

    // Issue ALL weight loads for BOTH iterations before the sync:
    // 16 x 16B idx + 16 x 16B residual + 8 scale loads, all independent.
    int4   idx[NITER][UPW];
    float4 r[NITER][UPW];
    float  s[NITER][UPW];
    #pragma unroll
    for (int it = 0; it < NITER; ++it) {
        const int k = kbase + it * KQ;
        const int g = k >> 7;
        #pragma unroll
        for (int u = 0; u < UPW; ++u) {
            const size_t off = (size_t)(o0 + u) * IN_DIM + k;
            idx[it][u] = *reinterpret_cast<const int4*>(&indices[off]);
            r[it][u]   = *reinterpret_cast<const float4*>(&residual[off]);
            s[it][u]   = scales[(o0 + u) * NGROUPS + g];
        }
    }

    __syncthreads();   // cb visible; weight loads still in flight

    // Dequantize both iterations (frees idx/r registers for the FMA phase)
    const float* cbw = &cb[wave * UPW * LEVELS];
    float w[NITER][UPW][4];
    #pragma unroll
    for (int it = 0; it < NITER; ++it)
        #pragma unroll
        for (int u = 0; u < UPW; ++u) {
            w[it][u][0] = fmaf(cbw[u * LEVELS + idx[it][u].x], s[it][u], r[it][u].x);
            w[it][u][1] = fmaf(cbw[u * LEVELS + idx[it][u].y], s[it][u], r[it][u].y);
            w[it][u][2] = fmaf(cbw[u * LEVELS + idx[it][u].z], s[it][u], r[it][u].z);
            w[it][u][3] = fmaf(cbw[u * LEVELS + idx[it][u].w], s[it][u], r[it][u].w);
        }

    // Batch FMA phase: acc accumulates across both iterations.
    float acc[BATCH * UPW];
    #pragma unroll
    for (int i = 0; i < BATCH * UPW; ++i) acc[i] = 0.f;

    #pragma unroll
    for (int it = 0; it < NITER; ++it) {
        const int k = kbase + it * KQ;
        #pragma unroll
        for (int b = 0; b < BATCH; ++b) {
            const float4 in4 = *reinterpret_cast<const float4*>(&inputs[b * IN_DIM + k]);
            #pragma unroll
            for (int u = 0; u < UPW; ++u) {
                float a = acc[b * UPW + u];
                a = fmaf(in4.x, w[it][u][0], a);
                a = fmaf(in4.y, w[it][u][1], a);
                a = fmaf(in4.z, w[it][u][2], a);
                a = fmaf(in4.w, w[it][u][3], a);
                acc[b * UPW + u] = a;
            }
        }
    }

    // fold-reduce across 64 lanes: lane l ends with total of acc[l]
#define FOLD(S, N)                                         \
    {                                                      \
        const bool hi = (lane & (S)) != 0;                 \
        _Pragma("unroll")                                  \
        for (int t = 0; t < (N) / 2; ++t) {                \
            float a  = acc[2 * t];                         \
            float b2 = acc[2 * t + 1];                     \
            float send = hi ? a : b2;                      \
            float recv = __shfl_xor(send, (S));            \
            acc[t] = (hi ? b2 : a) + recv;                 \
        }                                                  \
    }
    FOLD(1, 64)
    FOLD(2, 32)
    FOLD(4, 16)
    FOLD(8, 8)
    FOLD(16, 4)
    FOLD(32, 2)
#undef FOLD

    // acc index i == lane: i = b*UPW + u  ->  b = lane>>2, u = lane&3
    const int b_ = lane >> 2;
    const int u_ = lane & 3;
    float v = acc[0];
    if (ks == 0) v += bias[o0 + u_];
    atomicAdd(&out[b_ * UNITS + o0 + u_], v);
}

extern "C" void kernel_launch(void* const* d_in, const int* in_sizes, int n_in,
                              void* d_out, int out_size, void* d_ws, size_t ws_size,
                              hipStream_t stream)
{
    const float* inputs    = (const float*)d_in[0];
    const float* codebooks = (const float*)d_in[1];
    const float* scales    = (const float*)d_in[2];
    const float* residual  = (const float*)d_in[3];
    const float* bias      = (const float*)d_in[4];
    const int*   indices   = (const int*)d_in[5];
    float* out = (float*)d_out;

    // out is accumulated via atomics -> must start from zero every call
    hipMemsetAsync(d_out, 0, (size_t)out_size * sizeof(float), stream);

    dim3 grid((UNITS / UPB) * KSPLIT);   // 256 * 8 = 2048 blocks
    dim3 block(256);
    turbo_dense_kernel<<<grid, block, 0, stream>>>(inputs, codebooks, scales,
                                                   residual, bias, indices, out);
}